// Round 15
// baseline (185.026 us; speedup 1.0000x reference)
//
#include <hip/hip_runtime.h>
#include <hip/hip_bf16.h>

// MultiHeadAttentionNoBatch: T=2048, D_IN=1024, D_OUT=1024, H=16, Dh=64, fp32 in/out.
// bf16 hi/lo split pipeline. split(x,W)->bf16 hi/lo; qkv_proj (r12, 52.6us):
// grid 512, heavy Q/K 128x128 3-term 2-deep counted-vmcnt + light V 64x128.
// Flash attention: grid KV-split x2 (1024 blocks, 4 blocks/CU, critical path
// halved — r13 structure) + COALESCED partial writes via LDS stage (r14 epilogue;
// r13's scattered partials caused 187MB writes + 159MB RFO fetches).
// attn_merge (r13, verified) combines the two halves.
// NOTE: reference multiplies scores by sqrt(Dh)=8 -> folded into exp2 scale.

typedef __bf16 bf16x8 __attribute__((ext_vector_type(8)));
typedef __bf16 bf16x4 __attribute__((ext_vector_type(4)));
typedef float  f32x4  __attribute__((ext_vector_type(4)));
typedef float  f32x16 __attribute__((ext_vector_type(16)));
typedef unsigned int u32;
typedef u32 u32x2 __attribute__((ext_vector_type(2)));
typedef u32 u32x4 __attribute__((ext_vector_type(4)));

#define MFMA(a, b, c) __builtin_amdgcn_mfma_f32_16x16x32_bf16((a), (b), (c), 0, 0, 0)
#define MFMA32(a, b, c) __builtin_amdgcn_mfma_f32_32x32x16_bf16((a), (b), (c), 0, 0, 0)

#if __has_builtin(__builtin_amdgcn_exp2f)
#define EXP2F(x) __builtin_amdgcn_exp2f(x)
#else
#define EXP2F(x) exp2f(x)
#endif

constexpr int T = 2048, DIN = 1024, DOUT = 1024, NH = 16, DH = 64;
constexpr float SC = 11.5415603f;   // 8 * log2(e): scores scaled by sqrt(Dh)=8
constexpr float DEFER = 0.6931472f; // defer-max threshold

// workspace layout (bytes); total 40 MiB
constexpr size_t SZ_XMAT = (size_t)T * DIN * 2;     // 4 MiB
constexpr size_t SZ_WMAT = (size_t)DOUT * DIN * 2;  // 2 MiB
constexpr size_t OFF_XH = 0;
constexpr size_t OFF_XL = OFF_XH + SZ_XMAT;
constexpr size_t OFF_QH = OFF_XL + SZ_XMAT;
constexpr size_t OFF_QL = OFF_QH + SZ_XMAT;
constexpr size_t OFF_KH = OFF_QL + SZ_XMAT;
constexpr size_t OFF_KL = OFF_KH + SZ_XMAT;
constexpr size_t OFF_VT = OFF_KL + SZ_XMAT;         // V^T bf16 [1024][2048]
constexpr size_t OFF_W  = OFF_VT + SZ_XMAT;         // 3 x (W_hi, W_lo), 12 MiB
// regions dead after qkv_proj, reused by attention partials:
constexpr size_t OFF_P0 = OFF_XH;                    // half-0 partial O, 8 MiB
constexpr size_t OFF_P1 = OFF_W;                     // half-1 partial O, 8 MiB of 12
constexpr size_t OFF_ML = OFF_W + ((size_t)8 << 20); // m,L pairs: 2*32768*2 f32

__device__ __forceinline__ void gload_lds16(const void* g, void* l) {
  __builtin_amdgcn_global_load_lds(
      (const __attribute__((address_space(1))) void*)g,
      (__attribute__((address_space(3))) void*)l, 16, 0, 0);
}

// partner-lane (lane^32) value via permlane32_swap (VALU pipe, no LDS traffic)
__device__ __forceinline__ float xor32f(float x, int hi) {
#if __has_builtin(__builtin_amdgcn_permlane32_swap)
  const u32 xu = __builtin_bit_cast(u32, x);
  const u32x2 rp = __builtin_amdgcn_permlane32_swap(xu, xu, false, false);
  return __builtin_bit_cast(float, hi ? rp[0] : rp[1]);
#else
  return __shfl_xor(x, 32, 64);
#endif
}

// ---------------- split fp32 -> bf16 hi + bf16 lo (x and 3 W in one launch) ----
__global__ void split_all(const float* __restrict__ x, const float* __restrict__ wq,
                          const float* __restrict__ wk, const float* __restrict__ wv,
                          char* __restrict__ ws) {
  const int i = blockIdx.x * 256 + threadIdx.x;
  const float* src;
  __bf16 *hi, *lo;
  int off;
  if (i < T * DIN / 4) {
    src = x; off = i;
    hi = (__bf16*)(ws + OFF_XH);
    lo = (__bf16*)(ws + OFF_XL);
  } else {
    const int j = i - T * DIN / 4;
    const int z = j >> 18;          // DOUT*DIN/4 = 262144 = 2^18
    off = j & 262143;
    src = (z == 0) ? wq : ((z == 1) ? wk : wv);
    hi = (__bf16*)(ws + OFF_W + (size_t)z * 2 * SZ_WMAT);
    lo = hi + (size_t)DOUT * DIN;
  }
  const f32x4 v = ((const f32x4*)src)[off];
  bf16x4 h, l;
#pragma unroll
  for (int j = 0; j < 4; ++j) {
    const float xv = v[j];
    const __bf16 hh = (__bf16)xv;
    h[j] = hh;
    l[j] = (__bf16)(xv - (float)hh);
  }
  ((bf16x4*)hi)[off] = h;
  ((bf16x4*)lo)[off] = l;
}

// ---------------- heavy Q/K loop (r4/r8 structure): 128x128, 3-term ----------
__device__ __forceinline__ void proj_loop_qk(const __bf16* __restrict__ Ah,
                                             const __bf16* __restrict__ Al,
                                             const __bf16* __restrict__ Bh,
                                             const __bf16* __restrict__ Bl,
                                             __bf16* lds, int tm, int tn, int lane,
                                             int wv, f32x4 (&acc)[4][4]) {
  constexpr int BUF = 16384, BOFF = 8192;
  const int wm = wv >> 1, wn = wv & 1;
  const int q4 = lane >> 4, r16 = lane & 15;

  auto STAGE = [&](int ks, int buf) {
    const int k0 = ks * 32;
    __bf16* base = lds + buf * BUF;
#pragma unroll
    for (int j = 0; j < 2; ++j) {
      const int cbase = wv * 128 + j * 64;  // wave-uniform chunk base
      const int cidx = cbase + lane;        // chunk = kc*128 + row
      const int row = cidx & 127, kc = cidx >> 7;
      const size_t ga = (size_t)(tm + row) * DIN + k0 + kc * 8;
      const size_t gb = (size_t)(tn + row) * DIN + k0 + kc * 8;
      gload_lds16(Ah + ga, base + cbase * 8);
      gload_lds16(Bh + gb, base + BOFF + cbase * 8);
      gload_lds16(Al + ga, base + 4096 + cbase * 8);
      gload_lds16(Bl + gb, base + 12288 + cbase * 8);
    }
  };

  STAGE(0, 0);
  STAGE(1, 1);

  for (int ks = 0; ks < 32; ++ks) {
    const int buf = ks & 1;
    if (ks < 31) asm volatile("s_waitcnt vmcnt(8)" ::: "memory");
    else         asm volatile("s_waitcnt vmcnt(0)" ::: "memory");
    __builtin_amdgcn_s_barrier();
    __builtin_amdgcn_sched_barrier(0);

    const __bf16* ldsA = lds + buf * BUF;
    const __bf16* ldsB = ldsA + BOFF;

    bf16x8 fah[4], fbh[4], fal[4], fbl[4];
#pragma unroll
    for (int b = 0; b < 4; ++b) {
      const int ra = wm * 64 + b * 16 + r16;
      const int rb = wn * 64 + b * 16 + r16;
      fah[b] = *(const bf16x8*)(ldsA + (q4 * 128 + ra) * 8);
      fbh[b] = *(const bf16x8*)(ldsB + (q4 * 128 + rb) * 8);
      fal[b] = *(const bf16x8*)(ldsA + 4096 + (q4 * 128 + ra) * 8);
      fbl[b] = *(const bf16x8*)(ldsB + 4096 + (q4 * 128 + rb) * 8);
    }
    __builtin_amdgcn_s_setprio(1);
#pragma unroll
    for (int bm = 0; bm < 4; ++bm)
#pragma unroll
      for (int bn = 0; bn < 4; ++bn) {
        acc[bm][bn] = MFMA(fah[bm], fbh[bn], acc[bm][bn]);
        acc[bm][bn] = MFMA(fah[bm], fbl[bn], acc[bm][bn]);
        acc[bm][bn] = MFMA(fal[bm], fbh[bn], acc[bm][bn]);
      }
    __builtin_amdgcn_s_setprio(0);
    asm volatile("s_waitcnt lgkmcnt(0)" ::: "memory");
    __builtin_amdgcn_sched_barrier(0);
    __builtin_amdgcn_s_barrier();
    __builtin_amdgcn_sched_barrier(0);
    if (ks < 30) STAGE(ks + 2, buf);
  }
}

// grid 512: bids 0..127 Q, 128..255 K (heavy 128x128), 256..511 V (light 64x128).
__global__ __launch_bounds__(256, 2) void qkv_proj(char* ws) {
  const int bid = blockIdx.x;
  const int tid = threadIdx.x;
  const int lane = tid & 63, wv = tid >> 6;
  const int q4 = lane >> 4, r16 = lane & 15;

  __shared__ alignas(16) __bf16 lds[32768];  // 64 KB

  const __bf16* Ah = (const __bf16*)(ws + OFF_XH);
  const __bf16* Al = (const __bf16*)(ws + OFF_XL);

  if (bid < 256) {  // ---- heavy: Q or K, 128x128, 3-term ----
    const int z = bid >> 7;
    const int t_ = bid & 127;
    const int tm = (t_ >> 3) * 128;
    const int tn = (t_ & 7) * 128;
    const int wm = wv >> 1, wn = wv & 1;
    const __bf16* Bh = (const __bf16*)(ws + OFF_W + (size_t)z * 2 * SZ_WMAT);
    const __bf16* Bl = Bh + (size_t)DOUT * DIN;

    f32x4 acc[4][4] = {};
    proj_loop_qk(Ah, Al, Bh, Bl, lds, tm, tn, lane, wv, acc);

    __bf16* Oh = (__bf16*)(ws + (z == 0 ? OFF_QH : OFF_KH));
    __bf16* Ol = (__bf16*)(ws + (z == 0 ? OFF_QL : OFF_KL));
#pragma unroll
    for (int bm = 0; bm < 4; ++bm)
#pragma unroll
      for (int bn = 0; bn < 4; ++bn)
#pragma unroll
        for (int r = 0; r < 4; ++r) {
          const int t = tm + wm * 64 + bm * 16 + q4 * 4 + r;  // D: row=(l>>4)*4+r
          const int n = tn + wn * 64 + bn * 16 + r16;         // D: col=l&15
          const float v = acc[bm][bn][r];
          const __bf16 hh = (__bf16)v;
          Oh[(size_t)t * DOUT + n] = hh;
          Ol[(size_t)t * DOUT + n] = (__bf16)(v - (float)hh);
        }
  } else {  // ---- light: V, 64x128 tile, 1-term (hi only) ----
    const int vt = bid - 256;           // 256 tiles: 32 M x 8 N
    const int tm = (vt >> 3) * 64;
    const int tn = (vt & 7) * 128;
    const __bf16* Bh = (const __bf16*)(ws + OFF_W + 2 * 2 * SZ_WMAT);

    auto STAGE = [&](int ks, int buf) {
      const int k0 = ks * 32;
      __bf16* base = lds + buf * 6144;
      {  // A 64x32: 256 chunks, 1/thread
        const int cbase = wv * 64;
        const int c = cbase + lane;
        const int row = c & 63, kc = c >> 6;
        gload_lds16(Ah + (size_t)(tm + row) * DIN + k0 + kc * 8, base + cbase * 8);
      }
#pragma unroll
      for (int j = 0; j < 2; ++j) {  // B 128x32: 512 chunks, 2/thread
        const int cbase = wv * 128 + j * 64;
        const int c = cbase + lane;
        const int row = c & 127, kc = c >> 7;
        gload_lds16(Bh + (size_t)(tn + row) * DIN + k0 + kc * 8,
                    base + 2048 + cbase * 8);
      }
    };

    f32x4 acc[4][2] = {};
    STAGE(0, 0);
    STAGE(1, 1);
    for (int ks = 0; ks < 32; ++ks) {
      const int buf = ks & 1;
      if (ks < 31) asm volatile("s_waitcnt vmcnt(3)" ::: "memory");
      else         asm volatile("s_waitcnt vmcnt(0)" ::: "memory");
      __builtin_amdgcn_s_barrier();
      __builtin_amdgcn_sched_barrier(0);

      const __bf16* ldsA = lds + buf * 6144;
      const __bf16* ldsB = ldsA + 2048;
      bf16x8 fa[4], fb[2];
#pragma unroll
      for (int b = 0; b < 4; ++b)
        fa[b] = *(const bf16x8*)(ldsA + (q4 * 64 + b * 16 + r16) * 8);
#pragma unroll
      for (int b = 0; b < 2; ++b)
        fb[b] = *(const bf16x8*)(ldsB + (q4 * 128 + wv * 32 + b * 16 + r16) * 8);
      __builtin_amdgcn_s_setprio(1);
#pragma unroll
      for (int bm = 0; bm < 4; ++bm)
#pragma unroll
        for (int bn = 0; bn < 2; ++bn)
          acc[bm][bn] = MFMA(fa[bm], fb[bn], acc[bm][bn]);
      __builtin_amdgcn_s_setprio(0);
      asm volatile("s_waitcnt lgkmcnt(0)" ::: "memory");
      __builtin_amdgcn_sched_barrier(0);
      __builtin_amdgcn_s_barrier();
      __builtin_amdgcn_sched_barrier(0);
      if (ks < 30) STAGE(ks + 2, buf);
    }

    // transpose 64x128 tile through LDS -> V^T[1024][2048]
    __syncthreads();
    __bf16* tb = lds;  // [128 n][72]
#pragma unroll
    for (int bm = 0; bm < 4; ++bm)
#pragma unroll
      for (int bn = 0; bn < 2; ++bn)
#pragma unroll
        for (int r = 0; r < 4; ++r) {
          const int tl = bm * 16 + q4 * 4 + r;             // t-local 0..63
          const int nl = wv * 32 + bn * 16 + r16;          // n-local 0..127
          tb[(size_t)nl * 72 + tl] = (__bf16)acc[bm][bn][r];
        }
    __syncthreads();
    __bf16* Vt = (__bf16*)(ws + OFF_VT);
#pragma unroll
    for (int it = 0; it < 4; ++it) {
      const int cid = it * 256 + tid;       // 1024 chunks of 8
      const int nl = cid >> 3, tc = cid & 7;
      const bf16x8 vd = *(const bf16x8*)(tb + (size_t)nl * 72 + tc * 8);
      *(bf16x8*)(Vt + (size_t)(tn + nl) * T + tm + tc * 8) = vd;
    }
  }
}

// ---------------- attention partial: grid kv-split x2, 4 blocks/CU ----------------
// 1024 blocks = (kvhalf, h, 64q-tile); 4 waves = (qhalf, kvpar); single-buffer
// per-stream K LDS (r8 loop). Partials written COALESCED via LDS stage (r14):
// O*w -> P0/P1 as 1024 f32x4 full-line stores; (m,L) -> ML (512B/block).
__global__ __launch_bounds__(256, 4) void attn_part(const char* __restrict__ ws,
                                                    char* __restrict__ wso) {
  const int bid0 = blockIdx.x;
  const int kvhalf = bid0 >> 9;
  const int bid = bid0 & 511;
  const int h = bid & 15;
  const int qt = (bid < 256) ? (31 - (bid >> 4)) : ((bid - 256) >> 4);
  const int tid = threadIdx.x;
  const int lane = tid & 63, wid = tid >> 6;
  const int qhalf = wid & 1, kvpar = wid >> 1;
  const int r32 = lane & 31, hi = lane >> 5, hi8 = hi * 8;
  const int qg = qt * 64 + qhalf * 32 + r32;  // this lane's q row
  const int NT = qt + 1;                      // kv tiles of 64 (global)
  const int midNT = (NT + 1) >> 1;
  const int rb = kvhalf ? midNT : 0;          // this block's tile range
  const int re = kvhalf ? NT : midNT;
  const int n = re - rb;
  const int iters = (n + 1) >> 1;             // per-stream max length
  const int tBeg = kvpar ? (rb + iters) : rb;
  const int tEnd = kvpar ? re : (rb + iters);

  const __bf16* Qh = (const __bf16*)(ws + OFF_QH);
  const __bf16* Ql = (const __bf16*)(ws + OFF_QL);
  const __bf16* Kh = (const __bf16*)(ws + OFF_KH);
  const __bf16* Kl = (const __bf16*)(ws + OFF_KL);
  const __bf16* Vt = (const __bf16*)(ws + OFF_VT);

  __shared__ alignas(16) __bf16 sK[2][2][64 * 72];  // [kvpar][hi/lo], 36.9 KB

  // Q B-frags (col=lane&31=q, d=ds*16+hi*8+j) in registers
  bf16x8 fqh[4], fql[4];
#pragma unroll
  for (int ds = 0; ds < 4; ++ds) {
    const size_t off = (size_t)qg * DOUT + h * 64 + ds * 16 + hi8;
    fqh[ds] = *(const bf16x8*)(Qh + off);
    fql[ds] = *(const bf16x8*)(Ql + off);
  }

  // staging regs: each stream's 128 threads stage its own K tile (hi+lo = 16KB)
  bf16x8 st[8];
  const int hid = qhalf * 64 + lane;  // thread index within the stream
  auto ISSUE = [&](int t) {
    const int kv0 = t * 64;
#pragma unroll
    for (int j = 0; j < 4; ++j) {
      const int c = j * 128 + hid;
      const int row = c >> 3, dc = c & 7;
      const size_t ko = (size_t)(kv0 + row) * DOUT + h * 64 + dc * 8;
      st[j] = *(const bf16x8*)(Kh + ko);
      st[4 + j] = *(const bf16x8*)(Kl + ko);
    }
  };
  auto WRITE = [&]() {
#pragma unroll
    for (int j = 0; j < 4; ++j) {
      const int c = j * 128 + hid;
      const int row = c >> 3, dc = c & 7;
      *(bf16x8*)(&sK[kvpar][0][row * 72 + dc * 8]) = st[j];
      *(bf16x8*)(&sK[kvpar][1][row * 72 + dc * 8]) = st[4 + j];
    }
  };

  f32x16 acc0 = {}, acc1 = {};  // O^T: d-blocks 0,1; col=q, row=d (crow)
  float mrun = -1e30f, lrun = 0.f;

  if (tBeg < tEnd) ISSUE(tBeg);

  for (int it = 0; it < iters; ++it) {
    const int t = tBeg + it;
    const bool act = (t < tEnd);
    __builtin_amdgcn_s_barrier();  // own stream's previous compute done reading
    if (act) {
      WRITE();
      if (t + 1 < tEnd) ISSUE(t + 1);  // prefetch next tile's K into regs
    }
    asm volatile("s_waitcnt lgkmcnt(0)" ::: "memory");
    __builtin_amdgcn_sched_barrier(0);
    __builtin_amdgcn_s_barrier();  // buffer visible to both waves of the stream
    if (!act) continue;

    const int kv0 = t * 64;
    const bool dodiag = (t == NT - 1);
    const bool do1 = !(dodiag && qhalf == 0);  // upper kblk fully masked

    // V A-frags straight from L2 (issued early; consumed after softmax)
    bf16x8 va0[4], va1[4];
#pragma unroll
    for (int ks = 0; ks < 4; ++ks) {
      const size_t vo = (size_t)(h * 64 + r32) * T + kv0 + ks * 16 + hi8;
      va0[ks] = *(const bf16x8*)(Vt + vo);
      va1[ks] = *(const bf16x8*)(Vt + vo + (size_t)32 * T);
    }

    const __bf16* kbh = &sK[kvpar][0][0];
    const __bf16* kbl = &sK[kvpar][1][0];
    f32x16 s0 = {}, s1 = {};
    __builtin_amdgcn_s_setprio(1);
#pragma unroll
    for (int ds = 0; ds < 4; ++ds) {
      const int ko = ds * 16 + hi8;
      const bf16x8 kh0 = *(const bf16x8*)(kbh + r32 * 72 + ko);
      const bf16x8 kl0 = *(const bf16x8*)(kbl + r32 * 72 + ko);
      s0 = MFMA32(kh0, fqh[ds], s0);
      s0 = MFMA32(kl0, fqh[ds], s0);
      s0 = MFMA32(kh0, fql[ds], s0);
    }
    if (do1) {
#pragma unroll
      for (int ds = 0; ds < 4; ++ds) {
        const int ko = ds * 16 + hi8;
        const bf16x8 kh1 = *(const bf16x8*)(kbh + (32 + r32) * 72 + ko);
        const bf16x8 kl1 = *(const bf16x8*)(kbl + (32 + r32) * 72 + ko);
        s1 = MFMA32(kh1, fqh[ds], s1);
        s1 = MFMA32(kl1, fqh[ds], s1);
        s1 = MFMA32(kh1, fql[ds], s1);
      }
    }
    __builtin_amdgcn_s_setprio(0);

    if (dodiag) {  // causal mask: k > q (covers skipped s1 too)
#pragma unroll
      for (int r = 0; r < 16; ++r) {
        const int kr = (r & 3) + 8 * (r >> 2) + 4 * hi;
        if (kv0 + kr > qg) s0[r] = -1e30f;
        if (kv0 + 32 + kr > qg) s1[r] = -1e30f;
      }
    }

    // lane-local softmax (q = lane&31; partner lane^32 has same q)
    float mx = -1e30f;
#pragma unroll
    for (int r = 0; r < 16; ++r) {
      mx = fmaxf(mx, s0[r]);
      mx = fmaxf(mx, s1[r]);
    }
    mx = fmaxf(mx, xor32f(mx, hi));

    if (__any(mx - mrun > DEFER)) {  // defer-max
      const float mnew = fmaxf(mrun, mx);
      const float scale = EXP2F((mrun - mnew) * SC);
      mrun = mnew;
      lrun *= scale;
#pragma unroll
      for (int r = 0; r < 16; ++r) {
        acc0[r] *= scale;
        acc1[r] *= scale;
      }
    }
    const float mn2 = mrun * SC;

    float ps = 0.f;
#pragma unroll
    for (int r = 0; r < 16; ++r) {
      s0[r] = EXP2F(__builtin_fmaf(s0[r], SC, -mn2));
      s1[r] = EXP2F(__builtin_fmaf(s1[r], SC, -mn2));
      ps += s0[r] + s1[r];
    }
    ps += xor32f(ps, hi);
    lrun += ps;

    // P -> PV B-frags: frag[ks] = P[k=ks*16+hi*8+j][q]
    bf16x8 pb[4];
#pragma unroll
    for (int ks = 0; ks < 4; ++ks) {
      const int rb2 = (ks & 1) * 8;
      bf16x4 lo4, hi4;
#pragma unroll
      for (int j = 0; j < 4; ++j) {
        const float pl = (ks < 2) ? s0[rb2 + j] : s1[rb2 + j];
        const float ph = (ks < 2) ? s0[rb2 + 4 + j] : s1[rb2 + 4 + j];
        lo4[j] = (__bf16)pl;
        hi4[j] = (__bf16)ph;
      }
      const u32x2 L = __builtin_bit_cast(u32x2, lo4);
      const u32x2 H = __builtin_bit_cast(u32x2, hi4);
      u32x4 f;
#if __has_builtin(__builtin_amdgcn_permlane32_swap)
#pragma unroll
      for (int q = 0; q < 2; ++q) {
        const u32x2 rp = __builtin_amdgcn_permlane32_swap(L[q], H[q], false, false);
        f[q] = rp[0];
        f[2 + q] = rp[1];
      }
#else
#pragma unroll
      for (int q = 0; q < 2; ++q) {
        const u32 send = hi ? L[q] : H[q];
        const u32 recv = (u32)__shfl_xor((int)send, 32, 64);
        f[q] = hi ? recv : L[q];
        f[2 + q] = hi ? H[q] : recv;
      }
#endif
      pb[ks] = __builtin_bit_cast(bf16x8, f);
    }

    // O^T += V^T P
    __builtin_amdgcn_s_setprio(1);
#pragma unroll
    for (int ks = 0; ks < 4; ++ks) {
      acc0 = MFMA32(va0[ks], pb[ks], acc0);
      acc1 = MFMA32(va1[ks], pb[ks], acc1);
    }
    __builtin_amdgcn_s_setprio(0);
  }

  // ---- merge the two in-block streams; COALESCED unnormalized partial write ----
  __builtin_amdgcn_s_barrier();  // all compute done; sK reusable as scratch
  float* mg = (float*)&sK[0][0][0];   // stash: [qhalf*64+lane]*34 floats (17KB)
  float* og = mg + 4352;              // O stage: [64 rows][68 floats] (17KB)
  if (kvpar == 1) {
    float* p = mg + (qhalf * 64 + lane) * 34;
    p[0] = mrun;
    p[1] = lrun;
#pragma unroll
    for (int r = 0; r < 16; ++r) {
      p[2 + r] = acc0[r];
      p[18 + r] = acc1[r];
    }
  }
  asm volatile("s_waitcnt lgkmcnt(0)" ::: "memory");
  __builtin_amdgcn_s_barrier();
  if (kvpar == 0) {
    const float* p = mg + (qhalf * 64 + lane) * 34;
    const float m1 = p[0], l1 = p[1];
    const float M = fmaxf(mrun, m1);
    const float w0 = EXP2F((mrun - M) * SC);
    const float w1 = EXP2F((m1 - M) * SC);
    float* orow = og + (qhalf * 32 + r32) * 68;
#pragma unroll
    for (int r = 0; r < 16; ++r) {
      const int d = (r & 3) + 8 * (r >> 2) + 4 * hi;
      orow[d] = acc0[r] * w0 + p[2 + r] * w1;
      orow[32 + d] = acc1[r] * w0 + p[18 + r] * w1;
    }
    if (hi == 0) {
      float* ml = (float*)(wso + OFF_ML) + ((size_t)kvhalf * 32768 + qg * 16 + h) * 2;
      ml[0] = M;
      ml[1] = lrun * w0 + l1 * w1;
    }
  }
  asm volatile("s_waitcnt lgkmcnt(0)" ::: "memory");
  __builtin_amdgcn_s_barrier();
  // cooperative coalesced store: 64 rows x 64 floats = 1024 f32x4 full-line chunks
  float* Op = (float*)(wso + (kvhalf ? OFF_P1 : OFF_P0));
#pragma unroll
  for (int it = 0; it < 4; ++it) {
    const int cid = it * 256 + tid;
    const int row = cid >> 4, c4 = cid & 15;
    const f32x4 v = *(const f32x4*)(og + row * 68 + c4 * 4);
    *(f32x4*)(&Op[(size_t)(qt * 64 + row) * DOUT + h * 64 + c4 * 4]) = v;
  }
}

// ---------------- merge the two kv-halves -> final output (r13, verified) ------
__global__ void attn_merge(const char* __restrict__ ws, float* __restrict__ out) {
  const int g = blockIdx.x * 256 + threadIdx.x;  // 524288 f32x4 groups
  const int f = g * 4;
  const int q = f >> 10;
  const int h = (f & 1023) >> 6;
  const float* ml = (const float*)(ws + OFF_ML);
  const float m0 = ml[((size_t)q * 16 + h) * 2 + 0];
  const float L0 = ml[((size_t)q * 16 + h) * 2 + 1];
  const float m1 = ml[((size_t)32768 + q * 16 + h) * 2 + 0];
  const float L1 = ml[((size_t)32768 + q * 16 + h) * 2 + 1];
  const float M = fmaxf(m0, m1);
  const float w0 = EXP2F((m0 - M) * SC);
  const float w1 = EXP2F((m1 - M) * SC);
  const float rden = 1.0f / (L0 * w0 + L1 * w1);
  const f32x4 a = ((const f32x4*)(ws + OFF_P0))[g];
  const f32x4 b = ((const f32x4*)(ws + OFF_P1))[g];
  f32x4 o;
#pragma unroll
  for (int j = 0; j < 4; ++j) o[j] = (a[j] * w0 + b[j] * w1) * rden;
  ((f32x4*)out)[g] = o;
}

// ---------------- launch ----------------
extern "C" void kernel_launch(void* const* d_in, const int* in_sizes, int n_in,
                              void* d_out, int out_size, void* d_ws, size_t ws_size,
                              hipStream_t stream) {
  const float* x  = (const float*)d_in[0];
  const float* Wq = (const float*)d_in[1];
  const float* Wk = (const float*)d_in[2];
  const float* Wv = (const float*)d_in[3];
  char* ws = (char*)d_ws;

  split_all<<<5120, 256, 0, stream>>>(x, Wq, Wk, Wv, ws);
  qkv_proj<<<512, 256, 0, stream>>>(ws);
  attn_part<<<1024, 256, 0, stream>>>(ws, ws);
  attn_merge<<<2048, 256, 0, stream>>>(ws, (float*)d_out);
}

// Round 16
// 95.197 us; speedup vs baseline: 1.9436x; 1.9436x over previous
//
#include <hip/hip_runtime.h>
#include <hip/hip_bf16.h>

// MultiHeadAttentionNoBatch: T=2048, D_IN=1024, D_OUT=1024, H=16, Dh=64, fp32 in/out.
// bf16 hi/lo split pipeline (forced: 2-term/fp16 variants exceed the 0.1025
// threshold — measured r11, derived r15). split(x,W)->bf16 hi/lo; qkv_proj
// grid 512 = exactly 2 blocks/CU, paired heavy+light: blocks 0..255 = Q,K
// (128x128 tile, 3-term, 2-deep counted-vmcnt gload_lds pipeline, 64KB LDS);
// blocks 256..511 = V (64x128 tile, 1-term). Fused flash attention: 32x32x16
// swapped S^T=K Q^T (lane-local softmax), intra-block KV-split, dbuf K LDS
// (1 barrier/tile), V direct from L2, permlane32_swap P-pack, defer-max.
// Best measured config: 95.2us (r12). kv-split-via-workspace (r13/r15) and
// XCD swizzle (r10) regress; see session journal.
// NOTE: reference multiplies scores by sqrt(Dh)=8 -> folded into exp2 scale.

typedef __bf16 bf16x8 __attribute__((ext_vector_type(8)));
typedef __bf16 bf16x4 __attribute__((ext_vector_type(4)));
typedef float  f32x4  __attribute__((ext_vector_type(4)));
typedef float  f32x16 __attribute__((ext_vector_type(16)));
typedef unsigned int u32;
typedef u32 u32x2 __attribute__((ext_vector_type(2)));
typedef u32 u32x4 __attribute__((ext_vector_type(4)));

#define MFMA(a, b, c) __builtin_amdgcn_mfma_f32_16x16x32_bf16((a), (b), (c), 0, 0, 0)
#define MFMA32(a, b, c) __builtin_amdgcn_mfma_f32_32x32x16_bf16((a), (b), (c), 0, 0, 0)

#if __has_builtin(__builtin_amdgcn_exp2f)
#define EXP2F(x) __builtin_amdgcn_exp2f(x)
#else
#define EXP2F(x) exp2f(x)
#endif

constexpr int T = 2048, DIN = 1024, DOUT = 1024, NH = 16, DH = 64;
constexpr float SC = 11.5415603f;   // 8 * log2(e): scores scaled by sqrt(Dh)=8
constexpr float DEFER = 0.6931472f; // defer-max threshold

// workspace layout (bytes); total 40 MiB
constexpr size_t SZ_XMAT = (size_t)T * DIN * 2;     // 4 MiB
constexpr size_t SZ_WMAT = (size_t)DOUT * DIN * 2;  // 2 MiB
constexpr size_t OFF_XH = 0;
constexpr size_t OFF_XL = OFF_XH + SZ_XMAT;
constexpr size_t OFF_QH = OFF_XL + SZ_XMAT;
constexpr size_t OFF_QL = OFF_QH + SZ_XMAT;
constexpr size_t OFF_KH = OFF_QL + SZ_XMAT;
constexpr size_t OFF_KL = OFF_KH + SZ_XMAT;
constexpr size_t OFF_VT = OFF_KL + SZ_XMAT;         // V^T bf16 [1024][2048]
constexpr size_t OFF_W  = OFF_VT + SZ_XMAT;         // 3 x (W_hi, W_lo)

__device__ __forceinline__ void gload_lds16(const void* g, void* l) {
  __builtin_amdgcn_global_load_lds(
      (const __attribute__((address_space(1))) void*)g,
      (__attribute__((address_space(3))) void*)l, 16, 0, 0);
}

// partner-lane (lane^32) value via permlane32_swap (VALU pipe, no LDS traffic)
__device__ __forceinline__ float xor32f(float x, int hi) {
#if __has_builtin(__builtin_amdgcn_permlane32_swap)
  const u32 xu = __builtin_bit_cast(u32, x);
  const u32x2 rp = __builtin_amdgcn_permlane32_swap(xu, xu, false, false);
  return __builtin_bit_cast(float, hi ? rp[0] : rp[1]);
#else
  return __shfl_xor(x, 32, 64);
#endif
}

// ---------------- split fp32 -> bf16 hi + bf16 lo (x and 3 W in one launch) ----
__global__ void split_all(const float* __restrict__ x, const float* __restrict__ wq,
                          const float* __restrict__ wk, const float* __restrict__ wv,
                          char* __restrict__ ws) {
  const int i = blockIdx.x * 256 + threadIdx.x;
  const float* src;
  __bf16 *hi, *lo;
  int off;
  if (i < T * DIN / 4) {
    src = x; off = i;
    hi = (__bf16*)(ws + OFF_XH);
    lo = (__bf16*)(ws + OFF_XL);
  } else {
    const int j = i - T * DIN / 4;
    const int z = j >> 18;          // DOUT*DIN/4 = 262144 = 2^18
    off = j & 262143;
    src = (z == 0) ? wq : ((z == 1) ? wk : wv);
    hi = (__bf16*)(ws + OFF_W + (size_t)z * 2 * SZ_WMAT);
    lo = hi + (size_t)DOUT * DIN;
  }
  const f32x4 v = ((const f32x4*)src)[off];
  bf16x4 h, l;
#pragma unroll
  for (int j = 0; j < 4; ++j) {
    const float xv = v[j];
    const __bf16 hh = (__bf16)xv;
    h[j] = hh;
    l[j] = (__bf16)(xv - (float)hh);
  }
  ((bf16x4*)hi)[off] = h;
  ((bf16x4*)lo)[off] = l;
}

// ---------------- heavy Q/K loop (r4/r8 structure): 128x128, 3-term ----------
__device__ __forceinline__ void proj_loop_qk(const __bf16* __restrict__ Ah,
                                             const __bf16* __restrict__ Al,
                                             const __bf16* __restrict__ Bh,
                                             const __bf16* __restrict__ Bl,
                                             __bf16* lds, int tm, int tn, int lane,
                                             int wv, f32x4 (&acc)[4][4]) {
  constexpr int BUF = 16384, BOFF = 8192;
  const int wm = wv >> 1, wn = wv & 1;
  const int q4 = lane >> 4, r16 = lane & 15;

  auto STAGE = [&](int ks, int buf) {
    const int k0 = ks * 32;
    __bf16* base = lds + buf * BUF;
#pragma unroll
    for (int j = 0; j < 2; ++j) {
      const int cbase = wv * 128 + j * 64;  // wave-uniform chunk base
      const int cidx = cbase + lane;        // chunk = kc*128 + row
      const int row = cidx & 127, kc = cidx >> 7;
      const size_t ga = (size_t)(tm + row) * DIN + k0 + kc * 8;
      const size_t gb = (size_t)(tn + row) * DIN + k0 + kc * 8;
      gload_lds16(Ah + ga, base + cbase * 8);
      gload_lds16(Bh + gb, base + BOFF + cbase * 8);
      gload_lds16(Al + ga, base + 4096 + cbase * 8);
      gload_lds16(Bl + gb, base + 12288 + cbase * 8);
    }
  };

  STAGE(0, 0);
  STAGE(1, 1);

  for (int ks = 0; ks < 32; ++ks) {
    const int buf = ks & 1;
    if (ks < 31) asm volatile("s_waitcnt vmcnt(8)" ::: "memory");
    else         asm volatile("s_waitcnt vmcnt(0)" ::: "memory");
    __builtin_amdgcn_s_barrier();
    __builtin_amdgcn_sched_barrier(0);

    const __bf16* ldsA = lds + buf * BUF;
    const __bf16* ldsB = ldsA + BOFF;

    bf16x8 fah[4], fbh[4], fal[4], fbl[4];
#pragma unroll
    for (int b = 0; b < 4; ++b) {
      const int ra = wm * 64 + b * 16 + r16;
      const int rb = wn * 64 + b * 16 + r16;
      fah[b] = *(const bf16x8*)(ldsA + (q4 * 128 + ra) * 8);
      fbh[b] = *(const bf16x8*)(ldsB + (q4 * 128 + rb) * 8);
      fal[b] = *(const bf16x8*)(ldsA + 4096 + (q4 * 128 + ra) * 8);
      fbl[b] = *(const bf16x8*)(ldsB + 4096 + (q4 * 128 + rb) * 8);
    }
    __builtin_amdgcn_s_setprio(1);
#pragma unroll
    for (int bm = 0; bm < 4; ++bm)
#pragma unroll
      for (int bn = 0; bn < 4; ++bn) {
        acc[bm][bn] = MFMA(fah[bm], fbh[bn], acc[bm][bn]);
        acc[bm][bn] = MFMA(fah[bm], fbl[bn], acc[bm][bn]);
        acc[bm][bn] = MFMA(fal[bm], fbh[bn], acc[bm][bn]);
      }
    __builtin_amdgcn_s_setprio(0);
    asm volatile("s_waitcnt lgkmcnt(0)" ::: "memory");
    __builtin_amdgcn_sched_barrier(0);
    __builtin_amdgcn_s_barrier();
    __builtin_amdgcn_sched_barrier(0);
    if (ks < 30) STAGE(ks + 2, buf);
  }
}

// grid 512: bids 0..127 Q, 128..255 K (heavy 128x128), 256..511 V (light 64x128).
// Exactly 2 blocks/CU (64KB LDS each) -> breadth-first pairs heavy+light per CU.
__global__ __launch_bounds__(256, 2) void qkv_proj(char* ws) {
  const int bid = blockIdx.x;
  const int tid = threadIdx.x;
  const int lane = tid & 63, wv = tid >> 6;
  const int q4 = lane >> 4, r16 = lane & 15;

  __shared__ alignas(16) __bf16 lds[32768];  // 64 KB

  const __bf16* Ah = (const __bf16*)(ws + OFF_XH);
  const __bf16* Al = (const __bf16*)(ws + OFF_XL);

  if (bid < 256) {  // ---- heavy: Q or K, 128x128, 3-term ----
    const int z = bid >> 7;
    const int t_ = bid & 127;
    const int tm = (t_ >> 3) * 128;
    const int tn = (t_ & 7) * 128;
    const int wm = wv >> 1, wn = wv & 1;
    const __bf16* Bh = (const __bf16*)(ws + OFF_W + (size_t)z * 2 * SZ_WMAT);
    const __bf16* Bl = Bh + (size_t)DOUT * DIN;

    f32x4 acc[4][4] = {};
    proj_loop_qk(Ah, Al, Bh, Bl, lds, tm, tn, lane, wv, acc);

    __bf16* Oh = (__bf16*)(ws + (z == 0 ? OFF_QH : OFF_KH));
    __bf16* Ol = (__bf16*)(ws + (z == 0 ? OFF_QL : OFF_KL));
#pragma unroll
    for (int bm = 0; bm < 4; ++bm)
#pragma unroll
      for (int bn = 0; bn < 4; ++bn)
#pragma unroll
        for (int r = 0; r < 4; ++r) {
          const int t = tm + wm * 64 + bm * 16 + q4 * 4 + r;  // D: row=(l>>4)*4+r
          const int n = tn + wn * 64 + bn * 16 + r16;         // D: col=l&15
          const float v = acc[bm][bn][r];
          const __bf16 hh = (__bf16)v;
          Oh[(size_t)t * DOUT + n] = hh;
          Ol[(size_t)t * DOUT + n] = (__bf16)(v - (float)hh);
        }
  } else {  // ---- light: V, 64x128 tile, 1-term (hi only) ----
    const int vt = bid - 256;           // 256 tiles: 32 M x 8 N
    const int tm = (vt >> 3) * 64;
    const int tn = (vt & 7) * 128;
    const __bf16* Bh = (const __bf16*)(ws + OFF_W + 2 * 2 * SZ_WMAT);

    // buffer: A [kc4][row64][8] = 2048 elems, B [kc4][row128][8] = 4096; dbuf.
    auto STAGE = [&](int ks, int buf) {
      const int k0 = ks * 32;
      __bf16* base = lds + buf * 6144;
      {  // A 64x32: 256 chunks, 1/thread
        const int cbase = wv * 64;
        const int c = cbase + lane;
        const int row = c & 63, kc = c >> 6;
        gload_lds16(Ah + (size_t)(tm + row) * DIN + k0 + kc * 8, base + cbase * 8);
      }
#pragma unroll
      for (int j = 0; j < 2; ++j) {  // B 128x32: 512 chunks, 2/thread
        const int cbase = wv * 128 + j * 64;
        const int c = cbase + lane;
        const int row = c & 127, kc = c >> 7;
        gload_lds16(Bh + (size_t)(tn + row) * DIN + k0 + kc * 8,
                    base + 2048 + cbase * 8);
      }
    };

    f32x4 acc[4][2] = {};
    STAGE(0, 0);
    STAGE(1, 1);
    for (int ks = 0; ks < 32; ++ks) {
      const int buf = ks & 1;
      if (ks < 31) asm volatile("s_waitcnt vmcnt(3)" ::: "memory");
      else         asm volatile("s_waitcnt vmcnt(0)" ::: "memory");
      __builtin_amdgcn_s_barrier();
      __builtin_amdgcn_sched_barrier(0);

      const __bf16* ldsA = lds + buf * 6144;
      const __bf16* ldsB = ldsA + 2048;
      bf16x8 fa[4], fb[2];
#pragma unroll
      for (int b = 0; b < 4; ++b)
        fa[b] = *(const bf16x8*)(ldsA + (q4 * 64 + b * 16 + r16) * 8);
#pragma unroll
      for (int b = 0; b < 2; ++b)
        fb[b] = *(const bf16x8*)(ldsB + (q4 * 128 + wv * 32 + b * 16 + r16) * 8);
      __builtin_amdgcn_s_setprio(1);
#pragma unroll
      for (int bm = 0; bm < 4; ++bm)
#pragma unroll
        for (int bn = 0; bn < 2; ++bn)
          acc[bm][bn] = MFMA(fa[bm], fb[bn], acc[bm][bn]);
      __builtin_amdgcn_s_setprio(0);
      asm volatile("s_waitcnt lgkmcnt(0)" ::: "memory");
      __builtin_amdgcn_sched_barrier(0);
      __builtin_amdgcn_s_barrier();
      __builtin_amdgcn_sched_barrier(0);
      if (ks < 30) STAGE(ks + 2, buf);
    }

    // transpose 64x128 tile through LDS -> V^T[1024][2048]
    __syncthreads();
    __bf16* tb = lds;  // [128 n][72]
#pragma unroll
    for (int bm = 0; bm < 4; ++bm)
#pragma unroll
      for (int bn = 0; bn < 2; ++bn)
#pragma unroll
        for (int r = 0; r < 4; ++r) {
          const int tl = bm * 16 + q4 * 4 + r;             // t-local 0..63
          const int nl = wv * 32 + bn * 16 + r16;          // n-local 0..127
          tb[(size_t)nl * 72 + tl] = (__bf16)acc[bm][bn][r];
        }
    __syncthreads();
    __bf16* Vt = (__bf16*)(ws + OFF_VT);
#pragma unroll
    for (int it = 0; it < 4; ++it) {
      const int cid = it * 256 + tid;       // 1024 chunks of 8
      const int nl = cid >> 3, tc = cid & 7;
      const bf16x8 vd = *(const bf16x8*)(tb + (size_t)nl * 72 + tc * 8);
      *(bf16x8*)(Vt + (size_t)(tn + nl) * T + tm + tc * 8) = vd;
    }
  }
}

// ---------------- flash attention (r10/r12 structure: dbuf K, 1 barrier/tile) ---
__global__ __launch_bounds__(256, 2) void attn_kernel(const char* __restrict__ ws,
                                                      float* __restrict__ out) {
  const int bid = blockIdx.x;
  const int h = bid & 15;
  const int qt = (bid < 256) ? (31 - (bid >> 4)) : ((bid - 256) >> 4);
  const int tid = threadIdx.x;
  const int lane = tid & 63, wid = tid >> 6;
  const int qhalf = wid & 1, kvpar = wid >> 1;
  const int r32 = lane & 31, hi = lane >> 5, hi8 = hi * 8;
  const int qg = qt * 64 + qhalf * 32 + r32;  // this lane's q row
  const int NT = qt + 1;                      // kv tiles of 64
  const int mid = (NT + 1) >> 1;
  const int tBeg = kvpar ? mid : 0;
  const int tEnd = kvpar ? NT : mid;

  const __bf16* Qh = (const __bf16*)(ws + OFF_QH);
  const __bf16* Ql = (const __bf16*)(ws + OFF_QL);
  const __bf16* Kh = (const __bf16*)(ws + OFF_KH);
  const __bf16* Kl = (const __bf16*)(ws + OFF_KL);
  const __bf16* Vt = (const __bf16*)(ws + OFF_VT);

  __shared__ alignas(16) __bf16 sK[2][2][2][64 * 72];  // [kvpar][buf][hi/lo], 72KB

  // Q B-frags (col=lane&31=q, d=ds*16+hi*8+j) in registers
  bf16x8 fqh[4], fql[4];
#pragma unroll
  for (int ds = 0; ds < 4; ++ds) {
    const size_t off = (size_t)qg * DOUT + h * 64 + ds * 16 + hi8;
    fqh[ds] = *(const bf16x8*)(Qh + off);
    fql[ds] = *(const bf16x8*)(Ql + off);
  }

  // staging regs: each stream's 128 threads stage its own K tile (hi+lo = 16KB)
  bf16x8 st[8];
  const int hid = qhalf * 64 + lane;  // thread index within the stream
  auto ISSUE = [&](int t) {
    const int kv0 = t * 64;
#pragma unroll
    for (int j = 0; j < 4; ++j) {
      const int c = j * 128 + hid;
      const int row = c >> 3, dc = c & 7;
      const size_t ko = (size_t)(kv0 + row) * DOUT + h * 64 + dc * 8;
      st[j] = *(const bf16x8*)(Kh + ko);
      st[4 + j] = *(const bf16x8*)(Kl + ko);
    }
  };
  auto WRITE = [&](int b) {
#pragma unroll
    for (int j = 0; j < 4; ++j) {
      const int c = j * 128 + hid;
      const int row = c >> 3, dc = c & 7;
      *(bf16x8*)(&sK[kvpar][b][0][row * 72 + dc * 8]) = st[j];
      *(bf16x8*)(&sK[kvpar][b][1][row * 72 + dc * 8]) = st[4 + j];
    }
  };

  f32x16 acc0 = {}, acc1 = {};  // O^T: d-blocks 0,1; col=q, row=d (crow)
  float mrun = -1e30f, lrun = 0.f;

  // prologue: tile tBeg into buf 0; prefetch tile tBeg+1 into regs
  if (tBeg < tEnd) {
    ISSUE(tBeg);
    WRITE(0);  // compiler inserts vmcnt wait on st
    if (tBeg + 1 < tEnd) ISSUE(tBeg + 1);
  }
  asm volatile("s_waitcnt lgkmcnt(0)" ::: "memory");
  __builtin_amdgcn_sched_barrier(0);
  __builtin_amdgcn_s_barrier();
  __builtin_amdgcn_sched_barrier(0);

  for (int it = 0; it < mid; ++it) {
    const int t = tBeg + it;
    const int p = it & 1;
    if (t < tEnd) {
      // overlap: write next tile into alt buffer, refill staging regs
      if (t + 1 < tEnd) {
        WRITE(p ^ 1);
        if (t + 2 < tEnd) ISSUE(t + 2);
      }

      const int kv0 = t * 64;
      const bool dodiag = (t == NT - 1);
      const bool do1 = !(dodiag && qhalf == 0);  // upper kblk fully masked

      // V A-frags straight from L2 (issued early; consumed after softmax)
      bf16x8 va0[4], va1[4];
#pragma unroll
      for (int ks = 0; ks < 4; ++ks) {
        const size_t vo = (size_t)(h * 64 + r32) * T + kv0 + ks * 16 + hi8;
        va0[ks] = *(const bf16x8*)(Vt + vo);
        va1[ks] = *(const bf16x8*)(Vt + vo + (size_t)32 * T);
      }

      const __bf16* kbh = &sK[kvpar][p][0][0];
      const __bf16* kbl = &sK[kvpar][p][1][0];
      f32x16 s0 = {}, s1 = {};
      __builtin_amdgcn_s_setprio(1);
#pragma unroll
      for (int ds = 0; ds < 4; ++ds) {
        const int ko = ds * 16 + hi8;
        const bf16x8 kh0 = *(const bf16x8*)(kbh + r32 * 72 + ko);
        const bf16x8 kl0 = *(const bf16x8*)(kbl + r32 * 72 + ko);
        s0 = MFMA32(kh0, fqh[ds], s0);
        s0 = MFMA32(kl0, fqh[ds], s0);
        s0 = MFMA32(kh0, fql[ds], s0);
      }
      if (do1) {
#pragma unroll
        for (int ds = 0; ds < 4; ++ds) {
          const int ko = ds * 16 + hi8;
          const bf16x8 kh1 = *(const bf16x8*)(kbh + (32 + r32) * 72 + ko);
          const bf16x8 kl1 = *(const bf16x8*)(kbl + (32 + r32) * 72 + ko);
          s1 = MFMA32(kh1, fqh[ds], s1);
          s1 = MFMA32(kl1, fqh[ds], s1);
          s1 = MFMA32(kh1, fql[ds], s1);
        }
      }
      __builtin_amdgcn_s_setprio(0);

      if (dodiag) {  // causal mask: k > q (covers skipped s1 too)
#pragma unroll
        for (int r = 0; r < 16; ++r) {
          const int kr = (r & 3) + 8 * (r >> 2) + 4 * hi;
          if (kv0 + kr > qg) s0[r] = -1e30f;
          if (kv0 + 32 + kr > qg) s1[r] = -1e30f;
        }
      }

      // lane-local softmax (q = lane&31; partner lane^32 has same q)
      float mx = -1e30f;
#pragma unroll
      for (int r = 0; r < 16; ++r) {
        mx = fmaxf(mx, s0[r]);
        mx = fmaxf(mx, s1[r]);
      }
      mx = fmaxf(mx, xor32f(mx, hi));

      if (__any(mx - mrun > DEFER)) {  // defer-max
        const float mnew = fmaxf(mrun, mx);
        const float scale = EXP2F((mrun - mnew) * SC);
        mrun = mnew;
        lrun *= scale;
#pragma unroll
        for (int r = 0; r < 16; ++r) {
          acc0[r] *= scale;
          acc1[r] *= scale;
        }
      }
      const float mn2 = mrun * SC;

      float ps = 0.f;
#pragma unroll
      for (int r = 0; r < 16; ++r) {
        s0[r] = EXP2F(__builtin_fmaf(s0[r], SC, -mn2));
        s1[r] = EXP2F(__builtin_fmaf(s1[r], SC, -mn2));
        ps += s0[r] + s1[r];
      }
      ps += xor32f(ps, hi);
      lrun += ps;

      // P -> PV B-frags: frag[ks] = P[k=ks*16+hi*8+j][q]
      bf16x8 pb[4];
#pragma unroll
      for (int ks = 0; ks < 4; ++ks) {
        const int rb = (ks & 1) * 8;
        bf16x4 lo4, hi4;
#pragma unroll
        for (int j = 0; j < 4; ++j) {
          const float pl = (ks < 2) ? s0[rb + j] : s1[rb + j];
          const float ph = (ks < 2) ? s0[rb + 4 + j] : s1[rb + 4 + j];
          lo4[j] = (__bf16)pl;
          hi4[j] = (__bf16)ph;
        }
        const u32x2 L = __builtin_bit_cast(u32x2, lo4);
        const u32x2 H = __builtin_bit_cast(u32x2, hi4);
        u32x4 f;
#if __has_builtin(__builtin_amdgcn_permlane32_swap)
#pragma unroll
        for (int q = 0; q < 2; ++q) {
          const u32x2 rp = __builtin_amdgcn_permlane32_swap(L[q], H[q], false, false);
          f[q] = rp[0];
          f[2 + q] = rp[1];
        }
#else
#pragma unroll
        for (int q = 0; q < 2; ++q) {
          const u32 send = hi ? L[q] : H[q];
          const u32 recv = (u32)__shfl_xor((int)send, 32, 64);
          f[q] = hi ? recv : L[q];
          f[2 + q] = hi ? H[q] : recv;
        }
#endif
        pb[ks] = __builtin_bit_cast(bf16x8, f);
      }

      // O^T += V^T P
      __builtin_amdgcn_s_setprio(1);
#pragma unroll
      for (int ks = 0; ks < 4; ++ks) {
        acc0 = MFMA32(va0[ks], pb[ks], acc0);
        acc1 = MFMA32(va1[ks], pb[ks], acc1);
      }
      __builtin_amdgcn_s_setprio(0);
    }

    asm volatile("s_waitcnt lgkmcnt(0)" ::: "memory");  // drain reads+writes
    __builtin_amdgcn_sched_barrier(0);
    __builtin_amdgcn_s_barrier();  // single barrier per tile
    __builtin_amdgcn_sched_barrier(0);
  }

  // ---- merge the two kv-streams (per qhalf) through LDS ----
  float* mg = (float*)&sK[0][0][0][0];  // scratch: [qhalf*64+lane]*34 floats
  if (kvpar == 1) {
    float* p = mg + (qhalf * 64 + lane) * 34;
    p[0] = mrun;
    p[1] = lrun;
#pragma unroll
    for (int r = 0; r < 16; ++r) {
      p[2 + r] = acc0[r];
      p[18 + r] = acc1[r];
    }
  }
  asm volatile("s_waitcnt lgkmcnt(0)" ::: "memory");
  __builtin_amdgcn_s_barrier();
  if (kvpar == 0) {
    const float* p = mg + (qhalf * 64 + lane) * 34;
    const float m1 = p[0], l1 = p[1];
    const float M = fmaxf(mrun, m1);
    const float w0 = EXP2F((mrun - M) * SC);
    const float w1 = EXP2F((m1 - M) * SC);
    const float rl = 1.0f / (lrun * w0 + l1 * w1);
#pragma unroll
    for (int r = 0; r < 16; ++r) {
      const int d = (r & 3) + 8 * (r >> 2) + 4 * hi;
      out[(size_t)qg * DOUT + h * 64 + d] = (acc0[r] * w0 + p[2 + r] * w1) * rl;
      out[(size_t)qg * DOUT + h * 64 + 32 + d] = (acc1[r] * w0 + p[18 + r] * w1) * rl;
    }
  }
}

// ---------------- launch ----------------
extern "C" void kernel_launch(void* const* d_in, const int* in_sizes, int n_in,
                              void* d_out, int out_size, void* d_ws, size_t ws_size,
                              hipStream_t stream) {
  const float* x  = (const float*)d_in[0];
  const float* Wq = (const float*)d_in[1];
  const float* Wk = (const float*)d_in[2];
  const float* Wv = (const float*)d_in[3];
  char* ws = (char*)d_ws;

  split_all<<<5120, 256, 0, stream>>>(x, Wq, Wk, Wv, ws);
  qkv_proj<<<512, 256, 0, stream>>>(ws);
  attn_kernel<<<512, 256, 0, stream>>>(ws, (float*)d_out);
}

// Round 17
// 93.991 us; speedup vs baseline: 1.9686x; 1.0128x over previous
//
#include <hip/hip_runtime.h>
#include <hip/hip_bf16.h>

// MultiHeadAttentionNoBatch: T=2048, D_IN=1024, D_OUT=1024, H=16, Dh=64, fp32 in/out.
// bf16 hi/lo split pipeline (forced: fp16/2-term fail 0.1025 threshold — r11).
// split(x,W)->bf16 hi/lo; qkv_proj (52.6us, r12): grid 512 = 2 blocks/CU paired
// heavy Q/K 128x128 3-term + light V 64x128, 2-deep counted-vmcnt gload_lds.
// Flash attention: r12 structure + T15 CROSS-ITERATION PIPELINE: QK^T(t+1)
// (reads dbuf'd K, independent of softmax(t)) issued before softmax/PV(t) so
// MFMA pipe overlaps the serial VALU chain. One barrier/iter; invariant:
// body i = {QK(t+1) reads buf (i+1)&1 (written body i-1); SMPV(t);
// WRITE(buf i&1 <- tile t+2); barrier}.
// NOTE: reference multiplies scores by sqrt(Dh)=8 -> folded into exp2 scale.

typedef __bf16 bf16x8 __attribute__((ext_vector_type(8)));
typedef __bf16 bf16x4 __attribute__((ext_vector_type(4)));
typedef float  f32x4  __attribute__((ext_vector_type(4)));
typedef float  f32x16 __attribute__((ext_vector_type(16)));
typedef unsigned int u32;
typedef u32 u32x2 __attribute__((ext_vector_type(2)));
typedef u32 u32x4 __attribute__((ext_vector_type(4)));

#define MFMA(a, b, c) __builtin_amdgcn_mfma_f32_16x16x32_bf16((a), (b), (c), 0, 0, 0)
#define MFMA32(a, b, c) __builtin_amdgcn_mfma_f32_32x32x16_bf16((a), (b), (c), 0, 0, 0)

#if __has_builtin(__builtin_amdgcn_exp2f)
#define EXP2F(x) __builtin_amdgcn_exp2f(x)
#else
#define EXP2F(x) exp2f(x)
#endif

constexpr int T = 2048, DIN = 1024, DOUT = 1024, NH = 16, DH = 64;
constexpr float SC = 11.5415603f;   // 8 * log2(e): scores scaled by sqrt(Dh)=8
constexpr float DEFER = 0.6931472f; // defer-max threshold

// workspace layout (bytes); total 40 MiB
constexpr size_t SZ_XMAT = (size_t)T * DIN * 2;     // 4 MiB
constexpr size_t SZ_WMAT = (size_t)DOUT * DIN * 2;  // 2 MiB
constexpr size_t OFF_XH = 0;
constexpr size_t OFF_XL = OFF_XH + SZ_XMAT;
constexpr size_t OFF_QH = OFF_XL + SZ_XMAT;
constexpr size_t OFF_QL = OFF_QH + SZ_XMAT;
constexpr size_t OFF_KH = OFF_QL + SZ_XMAT;
constexpr size_t OFF_KL = OFF_KH + SZ_XMAT;
constexpr size_t OFF_VT = OFF_KL + SZ_XMAT;         // V^T bf16 [1024][2048]
constexpr size_t OFF_W  = OFF_VT + SZ_XMAT;         // 3 x (W_hi, W_lo)

__device__ __forceinline__ void gload_lds16(const void* g, void* l) {
  __builtin_amdgcn_global_load_lds(
      (const __attribute__((address_space(1))) void*)g,
      (__attribute__((address_space(3))) void*)l, 16, 0, 0);
}

// partner-lane (lane^32) value via permlane32_swap (VALU pipe, no LDS traffic)
__device__ __forceinline__ float xor32f(float x, int hi) {
#if __has_builtin(__builtin_amdgcn_permlane32_swap)
  const u32 xu = __builtin_bit_cast(u32, x);
  const u32x2 rp = __builtin_amdgcn_permlane32_swap(xu, xu, false, false);
  return __builtin_bit_cast(float, hi ? rp[0] : rp[1]);
#else
  return __shfl_xor(x, 32, 64);
#endif
}

// ---------------- split fp32 -> bf16 hi + bf16 lo (x and 3 W in one launch) ----
__global__ void split_all(const float* __restrict__ x, const float* __restrict__ wq,
                          const float* __restrict__ wk, const float* __restrict__ wv,
                          char* __restrict__ ws) {
  const int i = blockIdx.x * 256 + threadIdx.x;
  const float* src;
  __bf16 *hi, *lo;
  int off;
  if (i < T * DIN / 4) {
    src = x; off = i;
    hi = (__bf16*)(ws + OFF_XH);
    lo = (__bf16*)(ws + OFF_XL);
  } else {
    const int j = i - T * DIN / 4;
    const int z = j >> 18;          // DOUT*DIN/4 = 262144 = 2^18
    off = j & 262143;
    src = (z == 0) ? wq : ((z == 1) ? wk : wv);
    hi = (__bf16*)(ws + OFF_W + (size_t)z * 2 * SZ_WMAT);
    lo = hi + (size_t)DOUT * DIN;
  }
  const f32x4 v = ((const f32x4*)src)[off];
  bf16x4 h, l;
#pragma unroll
  for (int j = 0; j < 4; ++j) {
    const float xv = v[j];
    const __bf16 hh = (__bf16)xv;
    h[j] = hh;
    l[j] = (__bf16)(xv - (float)hh);
  }
  ((bf16x4*)hi)[off] = h;
  ((bf16x4*)lo)[off] = l;
}

// ---------------- heavy Q/K loop (r4/r8 structure): 128x128, 3-term ----------
__device__ __forceinline__ void proj_loop_qk(const __bf16* __restrict__ Ah,
                                             const __bf16* __restrict__ Al,
                                             const __bf16* __restrict__ Bh,
                                             const __bf16* __restrict__ Bl,
                                             __bf16* lds, int tm, int tn, int lane,
                                             int wv, f32x4 (&acc)[4][4]) {
  constexpr int BUF = 16384, BOFF = 8192;
  const int wm = wv >> 1, wn = wv & 1;
  const int q4 = lane >> 4, r16 = lane & 15;

  auto STAGE = [&](int ks, int buf) {
    const int k0 = ks * 32;
    __bf16* base = lds + buf * BUF;
#pragma unroll
    for (int j = 0; j < 2; ++j) {
      const int cbase = wv * 128 + j * 64;  // wave-uniform chunk base
      const int cidx = cbase + lane;        // chunk = kc*128 + row
      const int row = cidx & 127, kc = cidx >> 7;
      const size_t ga = (size_t)(tm + row) * DIN + k0 + kc * 8;
      const size_t gb = (size_t)(tn + row) * DIN + k0 + kc * 8;
      gload_lds16(Ah + ga, base + cbase * 8);
      gload_lds16(Bh + gb, base + BOFF + cbase * 8);
      gload_lds16(Al + ga, base + 4096 + cbase * 8);
      gload_lds16(Bl + gb, base + 12288 + cbase * 8);
    }
  };

  STAGE(0, 0);
  STAGE(1, 1);

  for (int ks = 0; ks < 32; ++ks) {
    const int buf = ks & 1;
    if (ks < 31) asm volatile("s_waitcnt vmcnt(8)" ::: "memory");
    else         asm volatile("s_waitcnt vmcnt(0)" ::: "memory");
    __builtin_amdgcn_s_barrier();
    __builtin_amdgcn_sched_barrier(0);

    const __bf16* ldsA = lds + buf * BUF;
    const __bf16* ldsB = ldsA + BOFF;

    bf16x8 fah[4], fbh[4], fal[4], fbl[4];
#pragma unroll
    for (int b = 0; b < 4; ++b) {
      const int ra = wm * 64 + b * 16 + r16;
      const int rb = wn * 64 + b * 16 + r16;
      fah[b] = *(const bf16x8*)(ldsA + (q4 * 128 + ra) * 8);
      fbh[b] = *(const bf16x8*)(ldsB + (q4 * 128 + rb) * 8);
      fal[b] = *(const bf16x8*)(ldsA + 4096 + (q4 * 128 + ra) * 8);
      fbl[b] = *(const bf16x8*)(ldsB + 4096 + (q4 * 128 + rb) * 8);
    }
    __builtin_amdgcn_s_setprio(1);
#pragma unroll
    for (int bm = 0; bm < 4; ++bm)
#pragma unroll
      for (int bn = 0; bn < 4; ++bn) {
        acc[bm][bn] = MFMA(fah[bm], fbh[bn], acc[bm][bn]);
        acc[bm][bn] = MFMA(fah[bm], fbl[bn], acc[bm][bn]);
        acc[bm][bn] = MFMA(fal[bm], fbh[bn], acc[bm][bn]);
      }
    __builtin_amdgcn_s_setprio(0);
    asm volatile("s_waitcnt lgkmcnt(0)" ::: "memory");
    __builtin_amdgcn_sched_barrier(0);
    __builtin_amdgcn_s_barrier();
    __builtin_amdgcn_sched_barrier(0);
    if (ks < 30) STAGE(ks + 2, buf);
  }
}

// grid 512: bids 0..127 Q, 128..255 K (heavy 128x128), 256..511 V (light 64x128).
__global__ __launch_bounds__(256, 2) void qkv_proj(char* ws) {
  const int bid = blockIdx.x;
  const int tid = threadIdx.x;
  const int lane = tid & 63, wv = tid >> 6;
  const int q4 = lane >> 4, r16 = lane & 15;

  __shared__ alignas(16) __bf16 lds[32768];  // 64 KB

  const __bf16* Ah = (const __bf16*)(ws + OFF_XH);
  const __bf16* Al = (const __bf16*)(ws + OFF_XL);

  if (bid < 256) {  // ---- heavy: Q or K, 128x128, 3-term ----
    const int z = bid >> 7;
    const int t_ = bid & 127;
    const int tm = (t_ >> 3) * 128;
    const int tn = (t_ & 7) * 128;
    const int wm = wv >> 1, wn = wv & 1;
    const __bf16* Bh = (const __bf16*)(ws + OFF_W + (size_t)z * 2 * SZ_WMAT);
    const __bf16* Bl = Bh + (size_t)DOUT * DIN;

    f32x4 acc[4][4] = {};
    proj_loop_qk(Ah, Al, Bh, Bl, lds, tm, tn, lane, wv, acc);

    __bf16* Oh = (__bf16*)(ws + (z == 0 ? OFF_QH : OFF_KH));
    __bf16* Ol = (__bf16*)(ws + (z == 0 ? OFF_QL : OFF_KL));
#pragma unroll
    for (int bm = 0; bm < 4; ++bm)
#pragma unroll
      for (int bn = 0; bn < 4; ++bn)
#pragma unroll
        for (int r = 0; r < 4; ++r) {
          const int t = tm + wm * 64 + bm * 16 + q4 * 4 + r;  // D: row=(l>>4)*4+r
          const int n = tn + wn * 64 + bn * 16 + r16;         // D: col=l&15
          const float v = acc[bm][bn][r];
          const __bf16 hh = (__bf16)v;
          Oh[(size_t)t * DOUT + n] = hh;
          Ol[(size_t)t * DOUT + n] = (__bf16)(v - (float)hh);
        }
  } else {  // ---- light: V, 64x128 tile, 1-term (hi only) ----
    const int vt = bid - 256;           // 256 tiles: 32 M x 8 N
    const int tm = (vt >> 3) * 64;
    const int tn = (vt & 7) * 128;
    const __bf16* Bh = (const __bf16*)(ws + OFF_W + 2 * 2 * SZ_WMAT);

    auto STAGE = [&](int ks, int buf) {
      const int k0 = ks * 32;
      __bf16* base = lds + buf * 6144;
      {  // A 64x32: 256 chunks, 1/thread
        const int cbase = wv * 64;
        const int c = cbase + lane;
        const int row = c & 63, kc = c >> 6;
        gload_lds16(Ah + (size_t)(tm + row) * DIN + k0 + kc * 8, base + cbase * 8);
      }
#pragma unroll
      for (int j = 0; j < 2; ++j) {  // B 128x32: 512 chunks, 2/thread
        const int cbase = wv * 128 + j * 64;
        const int c = cbase + lane;
        const int row = c & 127, kc = c >> 7;
        gload_lds16(Bh + (size_t)(tn + row) * DIN + k0 + kc * 8,
                    base + 2048 + cbase * 8);
      }
    };

    f32x4 acc[4][2] = {};
    STAGE(0, 0);
    STAGE(1, 1);
    for (int ks = 0; ks < 32; ++ks) {
      const int buf = ks & 1;
      if (ks < 31) asm volatile("s_waitcnt vmcnt(3)" ::: "memory");
      else         asm volatile("s_waitcnt vmcnt(0)" ::: "memory");
      __builtin_amdgcn_s_barrier();
      __builtin_amdgcn_sched_barrier(0);

      const __bf16* ldsA = lds + buf * 6144;
      const __bf16* ldsB = ldsA + 2048;
      bf16x8 fa[4], fb[2];
#pragma unroll
      for (int b = 0; b < 4; ++b)
        fa[b] = *(const bf16x8*)(ldsA + (q4 * 64 + b * 16 + r16) * 8);
#pragma unroll
      for (int b = 0; b < 2; ++b)
        fb[b] = *(const bf16x8*)(ldsB + (q4 * 128 + wv * 32 + b * 16 + r16) * 8);
      __builtin_amdgcn_s_setprio(1);
#pragma unroll
      for (int bm = 0; bm < 4; ++bm)
#pragma unroll
        for (int bn = 0; bn < 2; ++bn)
          acc[bm][bn] = MFMA(fa[bm], fb[bn], acc[bm][bn]);
      __builtin_amdgcn_s_setprio(0);
      asm volatile("s_waitcnt lgkmcnt(0)" ::: "memory");
      __builtin_amdgcn_sched_barrier(0);
      __builtin_amdgcn_s_barrier();
      __builtin_amdgcn_sched_barrier(0);
      if (ks < 30) STAGE(ks + 2, buf);
    }

    // transpose 64x128 tile through LDS -> V^T[1024][2048]
    __syncthreads();
    __bf16* tb = lds;  // [128 n][72]
#pragma unroll
    for (int bm = 0; bm < 4; ++bm)
#pragma unroll
      for (int bn = 0; bn < 2; ++bn)
#pragma unroll
        for (int r = 0; r < 4; ++r) {
          const int tl = bm * 16 + q4 * 4 + r;             // t-local 0..63
          const int nl = wv * 32 + bn * 16 + r16;          // n-local 0..127
          tb[(size_t)nl * 72 + tl] = (__bf16)acc[bm][bn][r];
        }
    __syncthreads();
    __bf16* Vt = (__bf16*)(ws + OFF_VT);
#pragma unroll
    for (int it = 0; it < 4; ++it) {
      const int cid = it * 256 + tid;       // 1024 chunks of 8
      const int nl = cid >> 3, tc = cid & 7;
      const bf16x8 vd = *(const bf16x8*)(tb + (size_t)nl * 72 + tc * 8);
      *(bf16x8*)(Vt + (size_t)(tn + nl) * T + tm + tc * 8) = vd;
    }
  }
}

// ---------------- flash attention: T15 cross-iteration pipeline ----------------
__global__ __launch_bounds__(256, 2) void attn_kernel(const char* __restrict__ ws,
                                                      float* __restrict__ out) {
  const int bid = blockIdx.x;
  const int h = bid & 15;
  const int qt = (bid < 256) ? (31 - (bid >> 4)) : ((bid - 256) >> 4);
  const int tid = threadIdx.x;
  const int lane = tid & 63, wid = tid >> 6;
  const int qhalf = wid & 1, kvpar = wid >> 1;
  const int r32 = lane & 31, hi = lane >> 5, hi8 = hi * 8;
  const int qg = qt * 64 + qhalf * 32 + r32;  // this lane's q row
  const int NT = qt + 1;                      // kv tiles of 64
  const int mid = (NT + 1) >> 1;              // loop count (same for all waves)
  const int tBeg = kvpar ? mid : 0;
  const int tEnd = kvpar ? NT : mid;

  const __bf16* Qh = (const __bf16*)(ws + OFF_QH);
  const __bf16* Ql = (const __bf16*)(ws + OFF_QL);
  const __bf16* Kh = (const __bf16*)(ws + OFF_KH);
  const __bf16* Kl = (const __bf16*)(ws + OFF_KL);
  const __bf16* Vt = (const __bf16*)(ws + OFF_VT);

  __shared__ alignas(16) __bf16 sK[2][2][2][64 * 72];  // [kvpar][buf][hi/lo], 72KB

  // Q B-frags (col=lane&31=q, d=ds*16+hi*8+j) in registers
  bf16x8 fqh[4], fql[4];
#pragma unroll
  for (int ds = 0; ds < 4; ++ds) {
    const size_t off = (size_t)qg * DOUT + h * 64 + ds * 16 + hi8;
    fqh[ds] = *(const bf16x8*)(Qh + off);
    fql[ds] = *(const bf16x8*)(Ql + off);
  }

  // staging regs: each stream's 128 threads stage its own K tile (hi+lo = 16KB)
  bf16x8 st[8];
  const int hid = qhalf * 64 + lane;  // thread index within the stream
  auto ISSUE = [&](int t) {
    const int kv0 = t * 64;
#pragma unroll
    for (int j = 0; j < 4; ++j) {
      const int c = j * 128 + hid;
      const int row = c >> 3, dc = c & 7;
      const size_t ko = (size_t)(kv0 + row) * DOUT + h * 64 + dc * 8;
      st[j] = *(const bf16x8*)(Kh + ko);
      st[4 + j] = *(const bf16x8*)(Kl + ko);
    }
  };
  auto WRITE = [&](int b) {
#pragma unroll
    for (int j = 0; j < 4; ++j) {
      const int c = j * 128 + hid;
      const int row = c >> 3, dc = c & 7;
      *(bf16x8*)(&sK[kvpar][b][0][row * 72 + dc * 8]) = st[j];
      *(bf16x8*)(&sK[kvpar][b][1][row * 72 + dc * 8]) = st[4 + j];
    }
  };

  f32x16 acc0 = {}, acc1 = {};  // O^T: d-blocks 0,1; col=q, row=d (crow)
  float mrun = -1e30f, lrun = 0.f;

  // QK^T for buf p -> (o0, o1); d1 = compute upper k-block
  auto QK = [&](int p, bool d1, f32x16& o0, f32x16& o1) {
    const __bf16* kbh = &sK[kvpar][p][0][0];
    const __bf16* kbl = &sK[kvpar][p][1][0];
    f32x16 a0 = {}, a1 = {};
    __builtin_amdgcn_s_setprio(1);
#pragma unroll
    for (int ds = 0; ds < 4; ++ds) {
      const int ko = ds * 16 + hi8;
      const bf16x8 kh0 = *(const bf16x8*)(kbh + r32 * 72 + ko);
      const bf16x8 kl0 = *(const bf16x8*)(kbl + r32 * 72 + ko);
      a0 = MFMA32(kh0, fqh[ds], a0);
      a0 = MFMA32(kl0, fqh[ds], a0);
      a0 = MFMA32(kh0, fql[ds], a0);
    }
    if (d1) {
#pragma unroll
      for (int ds = 0; ds < 4; ++ds) {
        const int ko = ds * 16 + hi8;
        const bf16x8 kh1 = *(const bf16x8*)(kbh + (32 + r32) * 72 + ko);
        const bf16x8 kl1 = *(const bf16x8*)(kbl + (32 + r32) * 72 + ko);
        a1 = MFMA32(kh1, fqh[ds], a1);
        a1 = MFMA32(kl1, fqh[ds], a1);
        a1 = MFMA32(kh1, fql[ds], a1);
      }
    }
    __builtin_amdgcn_s_setprio(0);
    o0 = a0;
    o1 = a1;  // when !d1: zeros; fully masked at SMPV (diag+qhalf0 case)
  };

  // softmax + pack + PV for tile t with scores (s0, s1)
  auto SMPV = [&](int t, f32x16& s0, f32x16& s1) {
    const int kv0 = t * 64;
    const bool dodiag = (t == NT - 1);

    // V A-frags straight from L2 (issued here; consumed after softmax)
    bf16x8 va0[4], va1[4];
#pragma unroll
    for (int ks = 0; ks < 4; ++ks) {
      const size_t vo = (size_t)(h * 64 + r32) * T + kv0 + ks * 16 + hi8;
      va0[ks] = *(const bf16x8*)(Vt + vo);
      va1[ks] = *(const bf16x8*)(Vt + vo + (size_t)32 * T);
    }

    if (dodiag) {  // causal mask: k > q (covers skipped upper block too)
#pragma unroll
      for (int r = 0; r < 16; ++r) {
        const int kr = (r & 3) + 8 * (r >> 2) + 4 * hi;
        if (kv0 + kr > qg) s0[r] = -1e30f;
        if (kv0 + 32 + kr > qg) s1[r] = -1e30f;
      }
    }

    float mx = -1e30f;
#pragma unroll
    for (int r = 0; r < 16; ++r) {
      mx = fmaxf(mx, s0[r]);
      mx = fmaxf(mx, s1[r]);
    }
    mx = fmaxf(mx, xor32f(mx, hi));

    if (__any(mx - mrun > DEFER)) {  // defer-max
      const float mnew = fmaxf(mrun, mx);
      const float scale = EXP2F((mrun - mnew) * SC);
      mrun = mnew;
      lrun *= scale;
#pragma unroll
      for (int r = 0; r < 16; ++r) {
        acc0[r] *= scale;
        acc1[r] *= scale;
      }
    }
    const float mn2 = mrun * SC;

    float ps = 0.f;
#pragma unroll
    for (int r = 0; r < 16; ++r) {
      s0[r] = EXP2F(__builtin_fmaf(s0[r], SC, -mn2));
      s1[r] = EXP2F(__builtin_fmaf(s1[r], SC, -mn2));
      ps += s0[r] + s1[r];
    }
    ps += xor32f(ps, hi);
    lrun += ps;

    // P -> PV B-frags: frag[ks] = P[k=ks*16+hi*8+j][q]
    bf16x8 pb[4];
#pragma unroll
    for (int ks = 0; ks < 4; ++ks) {
      const int rb = (ks & 1) * 8;
      bf16x4 lo4, hi4;
#pragma unroll
      for (int j = 0; j < 4; ++j) {
        const float pl = (ks < 2) ? s0[rb + j] : s1[rb + j];
        const float ph = (ks < 2) ? s0[rb + 4 + j] : s1[rb + 4 + j];
        lo4[j] = (__bf16)pl;
        hi4[j] = (__bf16)ph;
      }
      const u32x2 L = __builtin_bit_cast(u32x2, lo4);
      const u32x2 H = __builtin_bit_cast(u32x2, hi4);
      u32x4 f;
#if __has_builtin(__builtin_amdgcn_permlane32_swap)
#pragma unroll
      for (int q = 0; q < 2; ++q) {
        const u32x2 rp = __builtin_amdgcn_permlane32_swap(L[q], H[q], false, false);
        f[q] = rp[0];
        f[2 + q] = rp[1];
      }
#else
#pragma unroll
      for (int q = 0; q < 2; ++q) {
        const u32 send = hi ? L[q] : H[q];
        const u32 recv = (u32)__shfl_xor((int)send, 32, 64);
        f[q] = hi ? recv : L[q];
        f[2 + q] = hi ? H[q] : recv;
      }
#endif
      pb[ks] = __builtin_bit_cast(bf16x8, f);
    }

    __builtin_amdgcn_s_setprio(1);
#pragma unroll
    for (int ks = 0; ks < 4; ++ks) {
      acc0 = MFMA32(va0[ks], pb[ks], acc0);
      acc1 = MFMA32(va1[ks], pb[ks], acc1);
    }
    __builtin_amdgcn_s_setprio(0);
  };

  // ---- prologue: buf0 <- tile tBeg; st <- tile tBeg+1 ----
  if (tBeg < tEnd) {
    ISSUE(tBeg);
    WRITE(0);  // compiler inserts vmcnt wait on st
    if (tBeg + 1 < tEnd) ISSUE(tBeg + 1);
  }
  asm volatile("s_waitcnt lgkmcnt(0)" ::: "memory");
  __builtin_amdgcn_sched_barrier(0);
  __builtin_amdgcn_s_barrier();
  __builtin_amdgcn_sched_barrier(0);

  // ---- pre-iteration: QK(tBeg) -> sA; buf1 <- tile tBeg+1; st <- tBeg+2 ----
  f32x16 sA0 = {}, sA1 = {}, sB0 = {}, sB1 = {};
  if (tBeg < tEnd) {
    QK(0, !((tBeg == NT - 1) && qhalf == 0), sA0, sA1);
    if (tBeg + 1 < tEnd) {
      WRITE(1);
      if (tBeg + 2 < tEnd) ISSUE(tBeg + 2);
    }
  }
  asm volatile("s_waitcnt lgkmcnt(0)" ::: "memory");
  __builtin_amdgcn_sched_barrier(0);
  __builtin_amdgcn_s_barrier();
  __builtin_amdgcn_sched_barrier(0);

  // ---- pipelined main loop: body i = QK(t+1) || SMPV(t); WRITE(t+2) ----
  auto BODY = [&](int i, f32x16& c0, f32x16& c1, f32x16& n0, f32x16& n1) {
    const int t = tBeg + i;
    if (t + 1 < tEnd)
      QK((i + 1) & 1, !((t + 1 == NT - 1) && qhalf == 0), n0, n1);
    if (t < tEnd) SMPV(t, c0, c1);
    if (t + 2 < tEnd) {
      WRITE(i & 1);  // buf i&1 last read by QK(t) during body i-1 (barrier'd)
      if (t + 3 < tEnd) ISSUE(t + 3);
    }
    asm volatile("s_waitcnt lgkmcnt(0)" ::: "memory");
    __builtin_amdgcn_sched_barrier(0);
    __builtin_amdgcn_s_barrier();  // single barrier per iteration
    __builtin_amdgcn_sched_barrier(0);
  };

  for (int i = 0; i < mid; i += 2) {
    BODY(i, sA0, sA1, sB0, sB1);
    BODY(i + 1, sB0, sB1, sA0, sA1);  // padded body if i+1 >= mid (barrier only)
  }

  // ---- merge the two kv-streams (per qhalf) through LDS ----
  float* mg = (float*)&sK[0][0][0][0];  // scratch: [qhalf*64+lane]*34 floats
  if (kvpar == 1) {
    float* p = mg + (qhalf * 64 + lane) * 34;
    p[0] = mrun;
    p[1] = lrun;
#pragma unroll
    for (int r = 0; r < 16; ++r) {
      p[2 + r] = acc0[r];
      p[18 + r] = acc1[r];
    }
  }
  asm volatile("s_waitcnt lgkmcnt(0)" ::: "memory");
  __builtin_amdgcn_s_barrier();
  if (kvpar == 0) {
    const float* p = mg + (qhalf * 64 + lane) * 34;
    const float m1 = p[0], l1 = p[1];
    const float M = fmaxf(mrun, m1);
    const float w0 = EXP2F((mrun - M) * SC);
    const float w1 = EXP2F((m1 - M) * SC);
    const float rl = 1.0f / (lrun * w0 + l1 * w1);
#pragma unroll
    for (int r = 0; r < 16; ++r) {
      const int d = (r & 3) + 8 * (r >> 2) + 4 * hi;
      out[(size_t)qg * DOUT + h * 64 + d] = (acc0[r] * w0 + p[2 + r] * w1) * rl;
      out[(size_t)qg * DOUT + h * 64 + 32 + d] = (acc1[r] * w0 + p[18 + r] * w1) * rl;
    }
  }
}

// ---------------- launch ----------------
extern "C" void kernel_launch(void* const* d_in, const int* in_sizes, int n_in,
                              void* d_out, int out_size, void* d_ws, size_t ws_size,
                              hipStream_t stream) {
  const float* x  = (const float*)d_in[0];
  const float* Wq = (const float*)d_in[1];
  const float* Wk = (const float*)d_in[2];
  const float* Wv = (const float*)d_in[3];
  char* ws = (char*)d_ws;

  split_all<<<5120, 256, 0, stream>>>(x, Wq, Wk, Wv, ws);
  qkv_proj<<<512, 256, 0, stream>>>(ws);
  attn_kernel<<<512, 256, 0, stream>>>(ws, (float*)d_out);
}